// Round 16
// baseline (99.210 us; speedup 1.0000x reference)
//
#include <hip/hip_runtime.h>
#include <hip/hip_bf16.h>

// MoE top-2 + shared expert, bf16 MFMA path. Round 16.
// vs R15 (95.8us): GEMM K-loops become a counted-vmcnt 2-deep PLANE rotation
// (T4): two 32-k plane buffers (same 48KB LDS), stage it & it+1 up front,
// then per plane: vmcnt(3) [3 newer loads stay in flight across the barrier]
// -> s_barrier -> 16 MFMA -> s_barrier -> stage(it+2). R6's counted-vmcnt
// failure was gather-addressing overhead; brick reads are now linear so the
// overhead term is gone. gemm2 same (vmcnt(2)). All else = R15.

#define DIM 1024
#define NTOK 2048
#define NEXP 8
#define NENT 4096          // NTOK * 2
#define ROWS_CAP 8192      // padded grouped rows upper bound
#define MAX_TILES 64
#define MM (DIM * DIM)

typedef float f32x4 __attribute__((ext_vector_type(4)));
typedef __bf16 bf16x8 __attribute__((ext_vector_type(8)));

__device__ __forceinline__ unsigned short f2bf(float f) {
  unsigned int u = __builtin_bit_cast(unsigned int, f);
  unsigned int r = u + 0x7FFFu + ((u >> 16) & 1u);   // RNE
  return (unsigned short)(r >> 16);
}
__device__ __forceinline__ float bf2f(unsigned short h) {
  unsigned int u = ((unsigned int)h) << 16;
  return __builtin_bit_cast(float, u);
}
__device__ __forceinline__ void gload_lds16(const unsigned short* g, unsigned short* l) {
  __builtin_amdgcn_global_load_lds((__attribute__((address_space(1))) const void*)g,
                                   (__attribute__((address_space(3))) void*)l, 16, 0, 0);
}

// ---------------- brick transpose (R14-verified): 128n x 128k tile -> 4 bricks -----------------
__device__ __forceinline__ void brick_transpose(const float* __restrict__ src,
                                                unsigned short* __restrict__ dst,
                                                int n_blk, int k_blk,
                                                unsigned short* lds) {
  int c0 = n_blk * 128, r0 = k_blk * 128;
  int tid = threadIdx.x;
  int q = tid & 31;
  int kq0 = tid >> 5;

  const float* sp0 = src + (size_t)(r0 + kq0 * 4) * DIM + c0 + q * 4;
  const float* sp1 = sp0 + (size_t)64 * DIM;
  float4 v0 = *(const float4*)(sp0 + 0 * DIM);
  float4 v1 = *(const float4*)(sp0 + 1 * DIM);
  float4 v2 = *(const float4*)(sp0 + 2 * DIM);
  float4 v3 = *(const float4*)(sp0 + 3 * DIM);
  float4 v4 = *(const float4*)(sp1 + 0 * DIM);
  float4 v5 = *(const float4*)(sp1 + 1 * DIM);
  float4 v6 = *(const float4*)(sp1 + 2 * DIM);
  float4 v7 = *(const float4*)(sp1 + 3 * DIM);
  {
    float a0[4] = {v0.x, v0.y, v0.z, v0.w};
    float a1[4] = {v1.x, v1.y, v1.z, v1.w};
    float a2[4] = {v2.x, v2.y, v2.z, v2.w};
    float a3[4] = {v3.x, v3.y, v3.z, v3.w};
    float b0[4] = {v4.x, v4.y, v4.z, v4.w};
    float b1[4] = {v5.x, v5.y, v5.z, v5.w};
    float b2[4] = {v6.x, v6.y, v6.z, v6.w};
    float b3[4] = {v7.x, v7.y, v7.z, v7.w};
#pragma unroll
    for (int j = 0; j < 4; j++) {
      int row = q * 4 + j;
      {
        int kq = kq0;
        int ch = kq >> 1, half = kq & 1;
        unsigned int off = (unsigned int)row * 128 + ((ch ^ (row & 15)) * 8 + half * 4);
        uint2 p;
        p.x = f2bf(a0[j]) | ((unsigned int)f2bf(a1[j]) << 16);
        p.y = f2bf(a2[j]) | ((unsigned int)f2bf(a3[j]) << 16);
        *(uint2*)(lds + off) = p;
      }
      {
        int kq = kq0 + 16;
        int ch = kq >> 1, half = kq & 1;
        unsigned int off = (unsigned int)row * 128 + ((ch ^ (row & 15)) * 8 + half * 4);
        uint2 p;
        p.x = f2bf(b0[j]) | ((unsigned int)f2bf(b1[j]) << 16);
        p.y = f2bf(b2[j]) | ((unsigned int)f2bf(b3[j]) << 16);
        *(uint2*)(lds + off) = p;
      }
    }
  }
  __syncthreads();

  size_t bbase = ((size_t)n_blk * 32 + (size_t)k_blk * 4) * 4096;
#pragma unroll
  for (int i = 0; i < 4; i++) {
    int g = tid + i * 512;
    int kcr = g >> 9;
    int c = g & 511;
    int row = c >> 2, p = c & 3;
    int koff = (p - (row >> 1)) & 3;
    int ch = kcr * 4 + koff;
    uint4 val = *(const uint4*)(lds + (unsigned int)row * 128 + (ch ^ (row & 15)) * 8);
    *(uint4*)(dst + bbase + (size_t)g * 8) = val;
  }
}

// ---------------- K1: router (blocks 0..255) ∪ transpose(w1,w3,w1s,w3s) ------------------------
__global__ __launch_bounds__(512) void t13_router(
    const float* __restrict__ x, const float* __restrict__ gw,
    const float* __restrict__ w1, const float* __restrict__ w3,
    const float* __restrict__ w1s, const float* __restrict__ w3s,
    unsigned short* __restrict__ w1t, unsigned short* __restrict__ w3t,
    unsigned short* __restrict__ w1st, unsigned short* __restrict__ w3st,
    unsigned short* __restrict__ xbf,
    int* __restrict__ e0, int* __restrict__ e1,
    float* __restrict__ s0, float* __restrict__ s1) {
  __shared__ __align__(16) unsigned short lds[128 * 128];
  int b = blockIdx.x;
  if (b < 256) {
    int lane = threadIdx.x & 63;
    int t = b * 8 + (threadIdx.x >> 6);
    const float4* xr4 = (const float4*)(x + (size_t)t * DIM);
    float4 xv[4];
#pragma unroll
    for (int i = 0; i < 4; i++) xv[i] = xr4[i * 64 + lane];

    ushort4* xb4 = (ushort4*)(xbf + (size_t)t * DIM);
#pragma unroll
    for (int i = 0; i < 4; i++) {
      ushort4 o;
      o.x = f2bf(xv[i].x); o.y = f2bf(xv[i].y); o.z = f2bf(xv[i].z); o.w = f2bf(xv[i].w);
      xb4[i * 64 + lane] = o;
    }
    if (t == 0) {
      ushort4 zz; zz.x = zz.y = zz.z = zz.w = 0;
      ushort4* pb4 = (ushort4*)(xbf + (size_t)NTOK * DIM);
#pragma unroll
      for (int i = 0; i < 4; i++) pb4[i * 64 + lane] = zz;
    }

    float acc[NEXP];
#pragma unroll
    for (int e = 0; e < NEXP; e++) {
      const float4* g4 = (const float4*)(gw + (size_t)e * DIM);
      float a = 0.f;
#pragma unroll
      for (int i = 0; i < 4; i++) {
        float4 g = g4[i * 64 + lane];
        a += xv[i].x * g.x + xv[i].y * g.y + xv[i].z * g.z + xv[i].w * g.w;
      }
      acc[e] = a;
    }
#pragma unroll
    for (int e = 0; e < NEXP; e++) {
      float v = acc[e];
      for (int o = 32; o > 0; o >>= 1) v += __shfl_xor(v, o);
      acc[e] = v;
    }
    if (lane == 0) {
      float m = acc[0];
#pragma unroll
      for (int e = 1; e < NEXP; e++) m = fmaxf(m, acc[e]);
      float ex[NEXP]; float Z = 0.f;
#pragma unroll
      for (int e = 0; e < NEXP; e++) { ex[e] = __expf(acc[e] - m); Z += ex[e]; }
      float inv = 1.f / Z;
      float sc[NEXP];
#pragma unroll
      for (int e = 0; e < NEXP; e++) sc[e] = ex[e] * inv;
      int b0 = 0; float v0 = sc[0];
#pragma unroll
      for (int e = 1; e < NEXP; e++) if (sc[e] > v0) { v0 = sc[e]; b0 = e; }
      int b1 = -1; float v1 = -1.f;
#pragma unroll
      for (int e = 0; e < NEXP; e++) if (e != b0 && sc[e] > v1) { v1 = sc[e]; b1 = e; }
      e0[t] = b0; e1[t] = b1; s0[t] = v0; s1[t] = v1;
    }
  } else {
    int bb = b - 256;
    int slice = bb >> 6, s6 = bb & 63;
    int n_blk = s6 & 7, k_blk = s6 >> 3;
    const float* src; unsigned short* dst;
    if (slice < 8)       { src = w1 + (size_t)slice * MM;       dst = w1t + (size_t)slice * MM; }
    else if (slice < 16) { src = w3 + (size_t)(slice - 8) * MM; dst = w3t + (size_t)(slice - 8) * MM; }
    else if (slice == 16){ src = w1s; dst = w1st; }
    else                 { src = w3s; dst = w3st; }
    brick_transpose(src, dst, n_blk, k_blk, lds);
  }
}

// ---------------- deterministic grouped build: packed uint4 scan (128-row padding) -------------
__global__ __launch_bounds__(256) void build_groups(
    const int* __restrict__ e0, const int* __restrict__ e1,
    const float* __restrict__ s0, const float* __restrict__ s1,
    int* __restrict__ gtok, float* __restrict__ gsc, int* __restrict__ row_of,
    int* __restrict__ tile_e, int* __restrict__ tile_r0, int* __restrict__ ntiles,
    int* __restrict__ base8out) {
  __shared__ unsigned int wsum[4][4];
  __shared__ int offl[256][NEXP];
  __shared__ int lrl[256][NEXP];
  int t = threadIdx.x, lane = t & 63, wave = t >> 6;

  for (int i = t; i < ROWS_CAP; i += 256) { gtok[i] = NTOK; gsc[i] = 0.f; }

  unsigned int pc[4] = {0, 0, 0, 0};
#pragma unroll
  for (int i = 0; i < 16; i++) {
    int ent = t * 16 + i;
    int tok = ent >> 1;
    int e = (ent & 1) ? e1[tok] : e0[tok];
    unsigned int add = 1u << ((e & 1) * 16);
    int c = e >> 1;
    if (c == 0) pc[0] += add; else if (c == 1) pc[1] += add;
    else if (c == 2) pc[2] += add; else pc[3] += add;
  }
  unsigned int incl[4] = {pc[0], pc[1], pc[2], pc[3]};
#pragma unroll
  for (int o = 1; o < 64; o <<= 1) {
    unsigned int u0 = __shfl_up(incl[0], o), u1 = __shfl_up(incl[1], o);
    unsigned int u2 = __shfl_up(incl[2], o), u3 = __shfl_up(incl[3], o);
    if (lane >= o) { incl[0] += u0; incl[1] += u1; incl[2] += u2; incl[3] += u3; }
  }
  if (lane == 63) { wsum[wave][0] = incl[0]; wsum[wave][1] = incl[1];
                    wsum[wave][2] = incl[2]; wsum[wave][3] = incl[3]; }
  __syncthreads();
  unsigned int T[4], pre[4] = {0, 0, 0, 0};
#pragma unroll
  for (int c = 0; c < 4; c++)
    T[c] = wsum[0][c] + wsum[1][c] + wsum[2][c] + wsum[3][c];
#pragma unroll
  for (int w = 0; w < 3; w++)
    if (wave > w) { pre[0] += wsum[w][0]; pre[1] += wsum[w][1];
                    pre[2] += wsum[w][2]; pre[3] += wsum[w][3]; }
  int base[NEXP + 1];
  {
    int b = 0;
#pragma unroll
    for (int e = 0; e < NEXP; e++) {
      int tot = (int)((T[e >> 1] >> ((e & 1) * 16)) & 0xFFFFu);
      base[e] = b; b += (tot + 127) & ~127;
    }
    base[NEXP] = b;
  }
#pragma unroll
  for (int e = 0; e < NEXP; e++) {
    unsigned int ex = (incl[e >> 1] + pre[e >> 1] - pc[e >> 1]);
    offl[t][e] = (int)((ex >> ((e & 1) * 16)) & 0xFFFFu);
    lrl[t][e] = 0;
  }
  if (t == 0) {
    int nt = 0;
#pragma unroll
    for (int e = 0; e < NEXP; e++) {
      int tot = (int)((T[e >> 1] >> ((e & 1) * 16)) & 0xFFFFu);
      int ntl = (tot + 127) >> 7;
      for (int i = 0; i < ntl; i++) { tile_e[nt] = e; tile_r0[nt] = base[e] + i * 128; nt++; }
    }
    for (int i = 0; i < NTOK / 128; i++) { tile_e[nt] = NEXP; tile_r0[nt] = base[NEXP] + i * 128; nt++; }
    *ntiles = nt;
    *base8out = base[NEXP];
  }
  __syncthreads();

#pragma unroll
  for (int i = 0; i < 16; i++) {
    int ent = t * 16 + i;
    int tok = ent >> 1;
    int k = ent & 1;
    int e = k ? e1[tok] : e0[tok];
    float s = k ? s1[tok] : s0[tok];
    int pos = base[e] + offl[t][e] + lrl[t][e];
    lrl[t][e]++;
    gtok[pos] = tok; gsc[pos] = s; row_of[ent] = pos;
  }
  for (int i = t; i < NTOK; i += 256) { gtok[base[NEXP] + i] = i; gsc[base[NEXP] + i] = 1.0f; }
}

// ---------------- K3: gemm13 counted-vmcnt plane rotation ∪ transpose(w2,w2s) ------------------
// 2 plane-buffers (each As/Bs1/Bs3 8KB = 24KB); stage it,it+1; per plane:
// vmcnt(3) -> barrier -> 16 MFMA -> barrier -> stage(it+2). Waves 64x32.
__global__ __launch_bounds__(512, 4) void gemm13_t2(
    const unsigned short* __restrict__ xbf,
    const unsigned short* __restrict__ W1, const unsigned short* __restrict__ W1s,
    const unsigned short* __restrict__ W3, const unsigned short* __restrict__ W3s,
    const float* __restrict__ w2, const float* __restrict__ w2s,
    unsigned short* __restrict__ w2t, unsigned short* __restrict__ w2st,
    unsigned short* __restrict__ H,
    const int* __restrict__ gtok, const float* __restrict__ gsc,
    const int* __restrict__ tile_e, const int* __restrict__ tile_r0,
    const int* __restrict__ ntiles) {
  __shared__ __align__(16) char smem[49664];   // union: 32KB transpose | 48.5KB gemm13
  int b = blockIdx.x;
  if (b >= 512) {
    int bb = b - 512;
    int slice = bb >> 6, s6 = bb & 63;
    int n_blk = s6 & 7, k_blk = s6 >> 3;
    const float* src; unsigned short* dst;
    if (slice < 8) { src = w2 + (size_t)slice * MM; dst = w2t + (size_t)slice * MM; }
    else           { src = w2s; dst = w2st; }
    brick_transpose(src, dst, n_blk, k_blk, (unsigned short*)smem);
    return;
  }
  int ti = b >> 3;
  if (ti >= *ntiles) return;
  int e = tile_e[ti];
  int row0 = tile_r0[ti];
  int col0 = (b & 7) * 128;
  const unsigned short* B1 = (e < NEXP) ? (W1 + (size_t)e * MM) : W1s;
  const unsigned short* B3 = (e < NEXP) ? (W3 + (size_t)e * MM) : W3s;

  unsigned short* As  = (unsigned short*)smem;            // 2 x 8KB planes
  unsigned short* Bs1 = (unsigned short*)(smem + 16384);
  unsigned short* Bs3 = (unsigned short*)(smem + 32768);
  float* ss = (float*)(smem + 49152);                     // 512B

  int tid = threadIdx.x;
  int wave = tid >> 6, lane = tid & 63;
  int wrow = (wave >> 2) * 64, wcol = (wave & 3) * 32;

  if (tid < 128) ss[tid] = gsc[row0 + tid];   // consumed in epilogue (after many barriers)

  f32x4 acc1[4][2], acc3[4][2];
#pragma unroll
  for (int m = 0; m < 4; m++)
#pragma unroll
    for (int n = 0; n < 2; n++) { acc1[m][n] = f32x4{0.f,0.f,0.f,0.f}; acc3[m][n] = f32x4{0.f,0.f,0.f,0.f}; }

  int arow = tid >> 2;
  int akoff = (((tid & 3) - (arow >> 1)) & 3) * 8;
  const unsigned short* ga  = xbf + (size_t)gtok[row0 + arow] * DIM + akoff;
  const unsigned short* gb1 = B1 + ((size_t)(col0 >> 7) * 32) * 4096 + (size_t)tid * 8;
  const unsigned short* gb3 = B3 + ((size_t)(col0 >> 7) * 32) * 4096 + (size_t)tid * 8;
  unsigned short* lA  = As  + wave * 512;
  unsigned short* lB1 = Bs1 + wave * 512;
  unsigned short* lB3 = Bs3 + wave * 512;

  int kc = lane >> 4, rl = lane & 15;

#define STAGE13(P, IT)                                         \
  { gload_lds16(ga + (IT) * 32, lA + (P) * 4096);              \
    gload_lds16(gb1 + (size_t)(IT) * 4096, lB1 + (P) * 4096);  \
    gload_lds16(gb3 + (size_t)(IT) * 4096, lB3 + (P) * 4096); }

  STAGE13(0, 0);
  STAGE13(1, 1);
  for (int it = 0; it < 32; it++) {
    int p = it & 1;
    if (it < 31) asm volatile("s_waitcnt vmcnt(3)" ::: "memory");
    else         asm volatile("s_waitcnt vmcnt(0)" ::: "memory");
    __builtin_amdgcn_s_barrier();     // all waves' plane-it loads complete
    {
      const bf16x8* Ap  = (const bf16x8*)(As  + p * 4096);
      const bf16x8* B1p = (const bf16x8*)(Bs1 + p * 4096);
      const bf16x8* B3p = (const bf16x8*)(Bs3 + p * 4096);
      bf16x8 af[4], b1f[2], b3f[2];
#pragma unroll
      for (int m = 0; m < 4; m++) {
        int row = wrow + m * 16 + rl;
        af[m] = Ap[row * 4 + ((kc + (row >> 1)) & 3)];
      }
#pragma unroll
      for (int n = 0; n < 2; n++) {
        int row = wcol + n * 16 + rl;
        int pp = row * 4 + ((kc + (row >> 1)) & 3);
        b1f[n] = B1p[pp];
        b3f[n] = B3p[pp];
      }
#pragma unroll
      for (int m = 0; m < 4; m++)
#pragma unroll
        for (int n = 0; n < 2; n++) {
          acc1[m][n] = __builtin_amdgcn_mfma_f32_16x16x32_bf16(af[m], b1f[n], acc1[m][n], 0, 0, 0);
          acc3[m][n] = __builtin_amdgcn_mfma_f32_16x16x32_bf16(af[m], b3f[n], acc3[m][n], 0, 0, 0);
        }
    }
    __builtin_amdgcn_s_barrier();     // all reads of plane p done before overwrite
    asm volatile("" ::: "memory");
    if (it + 2 < 32) STAGE13(p, it + 2);
  }

  int rj = lane >> 4, cl = lane & 15;
#pragma unroll
  for (int m = 0; m < 4; m++)
#pragma unroll
    for (int n = 0; n < 2; n++)
#pragma unroll
      for (int j = 0; j < 4; j++) {
        int lr = wrow + m * 16 + rj * 4 + j;
        float s = ss[lr];
        float a = s * acc1[m][n][j];
        float g = s * acc3[m][n][j];
        float si = a / (1.f + __expf(-a));
        H[(size_t)(row0 + lr) * DIM + (col0 + wcol + n * 16 + cl)] = f2bf(si * g);
      }
}

// ---------------- gemm2: counted-vmcnt plane rotation; routb = H * W2_e (bf16 out) -------------
__global__ __launch_bounds__(512, 4) void gemm2(
    const unsigned short* __restrict__ A, const unsigned short* __restrict__ W,
    const unsigned short* __restrict__ Wsh, unsigned short* __restrict__ C,
    const int* __restrict__ tile_e, const int* __restrict__ tile_r0,
    const int* __restrict__ ntiles) {
  if ((int)blockIdx.y >= *ntiles) return;
  int e = tile_e[blockIdx.y];
  int row0 = tile_r0[blockIdx.y];
  int col0 = blockIdx.x * 128;
  const unsigned short* B = (e < NEXP) ? (W + (size_t)e * MM) : Wsh;

  __shared__ __align__(16) unsigned short As[2 * 4096];   // 2 x 8KB planes
  __shared__ __align__(16) unsigned short Bs[2 * 4096];

  int tid = threadIdx.x;
  int wave = tid >> 6, lane = tid & 63;
  int wrow = (wave & 3) * 32, wcol = (wave >> 2) * 64;

  f32x4 acc[2][4];
#pragma unroll
  for (int m = 0; m < 2; m++)
#pragma unroll
    for (int n = 0; n < 4; n++) acc[m][n] = f32x4{0.f, 0.f, 0.f, 0.f};

  int arow = tid >> 2;
  int akoff = (((tid & 3) - (arow >> 1)) & 3) * 8;
  const unsigned short* ga = A + (size_t)(row0 + arow) * DIM + akoff;
  const unsigned short* gb = B + ((size_t)(col0 >> 7) * 32) * 4096 + (size_t)tid * 8;
  unsigned short* lA = As + wave * 512;
  unsigned short* lB = Bs + wave * 512;

  int kc = lane >> 4, rl = lane & 15;

#define STAGE2(P, IT)                                        \
  { gload_lds16(ga + (IT) * 32, lA + (P) * 4096);            \
    gload_lds16(gb + (size_t)(IT) * 4096, lB + (P) * 4096); }

  STAGE2(0, 0);
  STAGE2(1, 1);
  for (int it = 0; it < 32; it++) {
    int p = it & 1;
    if (it < 31) asm volatile("s_waitcnt vmcnt(2)" ::: "memory");
    else         asm volatile("s_waitcnt vmcnt(0)" ::: "memory");
    __builtin_amdgcn_s_barrier();
    {
      const bf16x8* Ap = (const bf16x8*)(As + p * 4096);
      const bf16x8* Bp = (const bf16x8*)(Bs + p * 4096);
      bf16x8 af[2], bfr[4];
#pragma unroll
      for (int m = 0; m < 2; m++) {
        int row = wrow + m * 16 + rl;
        af[m] = Ap[row * 4 + ((kc + (row >> 1)) & 3)];
      }
#pragma unroll
      for (int n = 0; n < 4; n++) {
        int row = wcol + n * 16 + rl;
        bfr[n] = Bp[row * 4 + ((kc + (row >> 1)) & 3)];
      }
#pragma unroll
      for (int m = 0; m < 2; m++)
#pragma unroll
        for (int n = 0; n < 4; n++)
          acc[m][n] = __builtin_amdgcn_mfma_f32_16x16x32_bf16(af[m], bfr[n], acc[m][n], 0, 0, 0);
    }
    __builtin_amdgcn_s_barrier();
    asm volatile("" ::: "memory");
    if (it + 2 < 32) STAGE2(p, it + 2);
  }

  int rj = lane >> 4, cl = lane & 15;
#pragma unroll
  for (int m = 0; m < 2; m++)
#pragma unroll
    for (int n = 0; n < 4; n++)
#pragma unroll
      for (int j = 0; j < 4; j++) {
        int r = row0 + wrow + m * 16 + rj * 4 + j;
        int c = col0 + wcol + n * 16 + cl;
        C[(size_t)r * DIM + c] = f2bf(acc[m][n][j]);
      }
}

// ---------------- combine: out[t] = routb[r0] + routb[r1] + routb[shared] (bf16 in) ------------
__global__ __launch_bounds__(256) void combine(const unsigned short* __restrict__ routb,
                                               const int* __restrict__ row_of,
                                               const int* __restrict__ base8,
                                               float* __restrict__ out) {
  int t = blockIdx.x;
  int c = threadIdx.x * 4;
  int r0 = row_of[2 * t], r1 = row_of[2 * t + 1];
  int rs = *base8 + t;
  ushort4 v0 = *(const ushort4*)(routb + (size_t)r0 * DIM + c);
  ushort4 v1 = *(const ushort4*)(routb + (size_t)r1 * DIM + c);
  ushort4 v2 = *(const ushort4*)(routb + (size_t)rs * DIM + c);
  float4 o;
  o.x = bf2f(v0.x) + bf2f(v1.x) + bf2f(v2.x);
  o.y = bf2f(v0.y) + bf2f(v1.y) + bf2f(v2.y);
  o.z = bf2f(v0.z) + bf2f(v1.z) + bf2f(v2.z);
  o.w = bf2f(v0.w) + bf2f(v1.w) + bf2f(v2.w);
  *(float4*)(out + (size_t)t * DIM + c) = o;
}

extern "C" void kernel_launch(void* const* d_in, const int* in_sizes, int n_in,
                              void* d_out, int out_size, void* d_ws, size_t ws_size,
                              hipStream_t stream) {
  const float* x   = (const float*)d_in[0];
  const float* gw  = (const float*)d_in[1];
  const float* w1  = (const float*)d_in[2];
  const float* w2  = (const float*)d_in[3];
  const float* w3  = (const float*)d_in[4];
  const float* w1s = (const float*)d_in[5];
  const float* w2s = (const float*)d_in[6];
  const float* w3s = (const float*)d_in[7];
  float* out = (float*)d_out;
  char* ws = (char*)d_ws;

  const size_t MB = 1ull << 20;
  unsigned short* w1t  = (unsigned short*)(ws + 0 * MB);    // 16MB [8] brick-layout W1^T
  unsigned short* w3t  = (unsigned short*)(ws + 16 * MB);   // 16MB
  unsigned short* w2t  = (unsigned short*)(ws + 32 * MB);   // 16MB
  unsigned short* w1st = (unsigned short*)(ws + 48 * MB);   // 2MB
  unsigned short* w3st = (unsigned short*)(ws + 50 * MB);   // 2MB
  unsigned short* w2st = (unsigned short*)(ws + 52 * MB);   // 2MB
  unsigned short* xbf  = (unsigned short*)(ws + 54 * MB);   // 4MB+  [NTOK+1][1024] bf16
  unsigned short* hbuf = (unsigned short*)(ws + 60 * MB);   // 16MB [8192][1024] bf16
  unsigned short* routb= (unsigned short*)(ws + 76 * MB);   // 16MB [8192][1024] bf16
  char* meta = ws + 108 * MB;
  int*   e0p    = (int*)meta;
  int*   e1p    = e0p + NTOK;
  float* s0p    = (float*)(e1p + NTOK);
  float* s1p    = s0p + NTOK;
  int*   gtok   = (int*)(s1p + NTOK);
  float* gsc    = (float*)(gtok + ROWS_CAP);
  int*   row_of = (int*)(gsc + ROWS_CAP);
  int*   tile_e = row_of + NENT;
  int*   tile_r0= tile_e + MAX_TILES;
  int*   ntiles = tile_r0 + MAX_TILES;
  int*   base8  = ntiles + 1;

  // K1: router (256 blocks) ∪ transpose w1/w3/w1s/w3s (1152 blocks)
  t13_router<<<256 + 18 * 64, 512, 0, stream>>>(
      x, gw, w1, w3, w1s, w3s, w1t, w3t, w1st, w3st, xbf, e0p, e1p, s0p, s1p);
  // K2: deterministic group build
  build_groups<<<1, 256, 0, stream>>>(e0p, e1p, s0p, s1p, gtok, gsc, row_of,
                                      tile_e, tile_r0, ntiles, base8);
  // K3: gemm13 pipelined (512 blocks) ∪ transpose w2/w2s (576 blocks)
  gemm13_t2<<<512 + 9 * 64, 512, 0, stream>>>(
      xbf, w1t, w1st, w3t, w3st, w2, w2s, w2t, w2st, hbuf,
      gtok, gsc, tile_e, tile_r0, ntiles);
  // K4: gemm2 pipelined (bf16 out)
  dim3 gg(8, MAX_TILES);
  gemm2<<<gg, 512, 0, stream>>>(hbuf, w2t, w2st, routb, tile_e, tile_r0, ntiles);
  // K5: combine
  combine<<<NTOK, 256, 0, stream>>>(routb, row_of, base8, out);
}

// Round 17
// 94.313 us; speedup vs baseline: 1.0519x; 1.0519x over previous
//
#include <hip/hip_runtime.h>
#include <hip/hip_bf16.h>

// MoE top-2 + shared expert, bf16 MFMA path. Round 17.
// vs R15 (95.8us best): R16's counted-vmcnt rotation REVERTED (3rd pipelining
// failure on this structure — matches guide m99-m141). Two additive wins:
// (1) s_setprio(1) around gemm13's MFMA cluster only (K3 has real wave
// role-diversity: gemm ∥ transpose waves; gemm2 is lockstep -> skipped);
// (2) 3 transpose slices (w1[0..2]) moved from K1 into the build dispatch
// (192 extra blocks hide under build's ~4us). K1 = 15 slices.

#define DIM 1024
#define NTOK 2048
#define NEXP 8
#define NENT 4096          // NTOK * 2
#define ROWS_CAP 8192      // padded grouped rows upper bound
#define MAX_TILES 64
#define MM (DIM * DIM)

typedef float f32x4 __attribute__((ext_vector_type(4)));
typedef __bf16 bf16x8 __attribute__((ext_vector_type(8)));

__device__ __forceinline__ unsigned short f2bf(float f) {
  unsigned int u = __builtin_bit_cast(unsigned int, f);
  unsigned int r = u + 0x7FFFu + ((u >> 16) & 1u);   // RNE
  return (unsigned short)(r >> 16);
}
__device__ __forceinline__ float bf2f(unsigned short h) {
  unsigned int u = ((unsigned int)h) << 16;
  return __builtin_bit_cast(float, u);
}
__device__ __forceinline__ void gload_lds16(const unsigned short* g, unsigned short* l) {
  __builtin_amdgcn_global_load_lds((__attribute__((address_space(1))) const void*)g,
                                   (__attribute__((address_space(3))) void*)l, 16, 0, 0);
}

// ---------------- brick transpose (R14-verified): 128n x 128k tile -> 4 bricks -----------------
// Brick position (row, p) holds data k-chunk (p - (row>>1))&3; GEMM reads chunk kc at
// position (kc + (row>>1))&3. LDS staging swizzled ch^=(row&15). Requires 512 threads.
__device__ __forceinline__ void brick_transpose(const float* __restrict__ src,
                                                unsigned short* __restrict__ dst,
                                                int n_blk, int k_blk,
                                                unsigned short* lds) {
  int c0 = n_blk * 128, r0 = k_blk * 128;
  int tid = threadIdx.x;
  int q = tid & 31;
  int kq0 = tid >> 5;

  const float* sp0 = src + (size_t)(r0 + kq0 * 4) * DIM + c0 + q * 4;
  const float* sp1 = sp0 + (size_t)64 * DIM;
  float4 v0 = *(const float4*)(sp0 + 0 * DIM);
  float4 v1 = *(const float4*)(sp0 + 1 * DIM);
  float4 v2 = *(const float4*)(sp0 + 2 * DIM);
  float4 v3 = *(const float4*)(sp0 + 3 * DIM);
  float4 v4 = *(const float4*)(sp1 + 0 * DIM);
  float4 v5 = *(const float4*)(sp1 + 1 * DIM);
  float4 v6 = *(const float4*)(sp1 + 2 * DIM);
  float4 v7 = *(const float4*)(sp1 + 3 * DIM);
  {
    float a0[4] = {v0.x, v0.y, v0.z, v0.w};
    float a1[4] = {v1.x, v1.y, v1.z, v1.w};
    float a2[4] = {v2.x, v2.y, v2.z, v2.w};
    float a3[4] = {v3.x, v3.y, v3.z, v3.w};
    float b0[4] = {v4.x, v4.y, v4.z, v4.w};
    float b1[4] = {v5.x, v5.y, v5.z, v5.w};
    float b2[4] = {v6.x, v6.y, v6.z, v6.w};
    float b3[4] = {v7.x, v7.y, v7.z, v7.w};
#pragma unroll
    for (int j = 0; j < 4; j++) {
      int row = q * 4 + j;
      {
        int kq = kq0;
        int ch = kq >> 1, half = kq & 1;
        unsigned int off = (unsigned int)row * 128 + ((ch ^ (row & 15)) * 8 + half * 4);
        uint2 p;
        p.x = f2bf(a0[j]) | ((unsigned int)f2bf(a1[j]) << 16);
        p.y = f2bf(a2[j]) | ((unsigned int)f2bf(a3[j]) << 16);
        *(uint2*)(lds + off) = p;
      }
      {
        int kq = kq0 + 16;
        int ch = kq >> 1, half = kq & 1;
        unsigned int off = (unsigned int)row * 128 + ((ch ^ (row & 15)) * 8 + half * 4);
        uint2 p;
        p.x = f2bf(b0[j]) | ((unsigned int)f2bf(b1[j]) << 16);
        p.y = f2bf(b2[j]) | ((unsigned int)f2bf(b3[j]) << 16);
        *(uint2*)(lds + off) = p;
      }
    }
  }
  __syncthreads();

  size_t bbase = ((size_t)n_blk * 32 + (size_t)k_blk * 4) * 4096;
#pragma unroll
  for (int i = 0; i < 4; i++) {
    int g = tid + i * 512;
    int kcr = g >> 9;
    int c = g & 511;
    int row = c >> 2, p = c & 3;
    int koff = (p - (row >> 1)) & 3;
    int ch = kcr * 4 + koff;
    uint4 val = *(const uint4*)(lds + (unsigned int)row * 128 + (ch ^ (row & 15)) * 8);
    *(uint4*)(dst + bbase + (size_t)g * 8) = val;
  }
}

// ---------------- K1: router (blocks 0..255) ∪ transpose(w1[3..7],w3,w1s,w3s: 15 slices) -------
__global__ __launch_bounds__(512) void t13_router(
    const float* __restrict__ x, const float* __restrict__ gw,
    const float* __restrict__ w1, const float* __restrict__ w3,
    const float* __restrict__ w1s, const float* __restrict__ w3s,
    unsigned short* __restrict__ w1t, unsigned short* __restrict__ w3t,
    unsigned short* __restrict__ w1st, unsigned short* __restrict__ w3st,
    unsigned short* __restrict__ xbf,
    int* __restrict__ e0, int* __restrict__ e1,
    float* __restrict__ s0, float* __restrict__ s1) {
  __shared__ __align__(16) unsigned short lds[128 * 128];
  int b = blockIdx.x;
  if (b < 256) {
    int lane = threadIdx.x & 63;
    int t = b * 8 + (threadIdx.x >> 6);
    const float4* xr4 = (const float4*)(x + (size_t)t * DIM);
    float4 xv[4];
#pragma unroll
    for (int i = 0; i < 4; i++) xv[i] = xr4[i * 64 + lane];

    ushort4* xb4 = (ushort4*)(xbf + (size_t)t * DIM);
#pragma unroll
    for (int i = 0; i < 4; i++) {
      ushort4 o;
      o.x = f2bf(xv[i].x); o.y = f2bf(xv[i].y); o.z = f2bf(xv[i].z); o.w = f2bf(xv[i].w);
      xb4[i * 64 + lane] = o;
    }
    if (t == 0) {
      ushort4 zz; zz.x = zz.y = zz.z = zz.w = 0;
      ushort4* pb4 = (ushort4*)(xbf + (size_t)NTOK * DIM);
#pragma unroll
      for (int i = 0; i < 4; i++) pb4[i * 64 + lane] = zz;
    }

    float acc[NEXP];
#pragma unroll
    for (int e = 0; e < NEXP; e++) {
      const float4* g4 = (const float4*)(gw + (size_t)e * DIM);
      float a = 0.f;
#pragma unroll
      for (int i = 0; i < 4; i++) {
        float4 g = g4[i * 64 + lane];
        a += xv[i].x * g.x + xv[i].y * g.y + xv[i].z * g.z + xv[i].w * g.w;
      }
      acc[e] = a;
    }
#pragma unroll
    for (int e = 0; e < NEXP; e++) {
      float v = acc[e];
      for (int o = 32; o > 0; o >>= 1) v += __shfl_xor(v, o);
      acc[e] = v;
    }
    if (lane == 0) {
      float m = acc[0];
#pragma unroll
      for (int e = 1; e < NEXP; e++) m = fmaxf(m, acc[e]);
      float ex[NEXP]; float Z = 0.f;
#pragma unroll
      for (int e = 0; e < NEXP; e++) { ex[e] = __expf(acc[e] - m); Z += ex[e]; }
      float inv = 1.f / Z;
      float sc[NEXP];
#pragma unroll
      for (int e = 0; e < NEXP; e++) sc[e] = ex[e] * inv;
      int b0 = 0; float v0 = sc[0];
#pragma unroll
      for (int e = 1; e < NEXP; e++) if (sc[e] > v0) { v0 = sc[e]; b0 = e; }
      int b1 = -1; float v1 = -1.f;
#pragma unroll
      for (int e = 0; e < NEXP; e++) if (e != b0 && sc[e] > v1) { v1 = sc[e]; b1 = e; }
      e0[t] = b0; e1[t] = b1; s0[t] = v0; s1[t] = v1;
    }
  } else {
    int bb = b - 256;
    int slice = bb >> 6, s6 = bb & 63;
    int n_blk = s6 & 7, k_blk = s6 >> 3;
    const float* src; unsigned short* dst;
    if (slice < 5)       { src = w1 + (size_t)(slice + 3) * MM; dst = w1t + (size_t)(slice + 3) * MM; }
    else if (slice < 13) { src = w3 + (size_t)(slice - 5) * MM; dst = w3t + (size_t)(slice - 5) * MM; }
    else if (slice == 13){ src = w1s; dst = w1st; }
    else                 { src = w3s; dst = w3st; }
    brick_transpose(src, dst, n_blk, k_blk, lds);
  }
}

// ---------------- K2: build_groups (block 0) ∪ transpose(w1[0..2]: 192 blocks) -----------------
// 512 threads; build phases guarded to tid<256, barriers unconditional.
__global__ __launch_bounds__(512) void build_t(
    const int* __restrict__ e0, const int* __restrict__ e1,
    const float* __restrict__ s0, const float* __restrict__ s1,
    const float* __restrict__ w1, unsigned short* __restrict__ w1t,
    int* __restrict__ gtok, float* __restrict__ gsc, int* __restrict__ row_of,
    int* __restrict__ tile_e, int* __restrict__ tile_r0, int* __restrict__ ntiles,
    int* __restrict__ base8out) {
  __shared__ __align__(16) unsigned short lds[128 * 128];   // transpose role (32KB)
  __shared__ unsigned int wsum[4][4];
  __shared__ int offl[256][NEXP];
  __shared__ int lrl[256][NEXP];

  int b = blockIdx.x;
  if (b > 0) {
    int bb = b - 1;
    int slice = bb >> 6, s6 = bb & 63;
    brick_transpose(w1 + (size_t)slice * MM, w1t + (size_t)slice * MM,
                    s6 & 7, s6 >> 3, lds);
    return;
  }

  int t = threadIdx.x, lane = t & 63, wave = t >> 6;
  bool act = t < 256;

  for (int i = t; i < ROWS_CAP; i += 512) { gtok[i] = NTOK; gsc[i] = 0.f; }  // pad -> zero row

  unsigned int pc[4] = {0, 0, 0, 0};
  if (act) {
#pragma unroll
    for (int i = 0; i < 16; i++) {
      int ent = t * 16 + i;
      int tok = ent >> 1;
      int e = (ent & 1) ? e1[tok] : e0[tok];
      unsigned int add = 1u << ((e & 1) * 16);
      int c = e >> 1;
      if (c == 0) pc[0] += add; else if (c == 1) pc[1] += add;
      else if (c == 2) pc[2] += add; else pc[3] += add;
    }
  }
  unsigned int incl[4] = {pc[0], pc[1], pc[2], pc[3]};
#pragma unroll
  for (int o = 1; o < 64; o <<= 1) {
    unsigned int u0 = __shfl_up(incl[0], o), u1 = __shfl_up(incl[1], o);
    unsigned int u2 = __shfl_up(incl[2], o), u3 = __shfl_up(incl[3], o);
    if (lane >= o) { incl[0] += u0; incl[1] += u1; incl[2] += u2; incl[3] += u3; }
  }
  if (act && lane == 63) { wsum[wave][0] = incl[0]; wsum[wave][1] = incl[1];
                           wsum[wave][2] = incl[2]; wsum[wave][3] = incl[3]; }
  __syncthreads();
  unsigned int T[4], pre[4] = {0, 0, 0, 0};
#pragma unroll
  for (int c = 0; c < 4; c++)
    T[c] = wsum[0][c] + wsum[1][c] + wsum[2][c] + wsum[3][c];
#pragma unroll
  for (int w = 0; w < 3; w++)
    if (wave > w) { pre[0] += wsum[w][0]; pre[1] += wsum[w][1];
                    pre[2] += wsum[w][2]; pre[3] += wsum[w][3]; }
  int base[NEXP + 1];
  {
    int bsum = 0;
#pragma unroll
    for (int e = 0; e < NEXP; e++) {
      int tot = (int)((T[e >> 1] >> ((e & 1) * 16)) & 0xFFFFu);
      base[e] = bsum; bsum += (tot + 127) & ~127;
    }
    base[NEXP] = bsum;
  }
  if (act) {
#pragma unroll
    for (int e = 0; e < NEXP; e++) {
      unsigned int ex = (incl[e >> 1] + pre[e >> 1] - pc[e >> 1]);
      offl[t][e] = (int)((ex >> ((e & 1) * 16)) & 0xFFFFu);
      lrl[t][e] = 0;
    }
  }
  if (t == 0) {
    int nt = 0;
#pragma unroll
    for (int e = 0; e < NEXP; e++) {
      int tot = (int)((T[e >> 1] >> ((e & 1) * 16)) & 0xFFFFu);
      int ntl = (tot + 127) >> 7;
      for (int i = 0; i < ntl; i++) { tile_e[nt] = e; tile_r0[nt] = base[e] + i * 128; nt++; }
    }
    for (int i = 0; i < NTOK / 128; i++) { tile_e[nt] = NEXP; tile_r0[nt] = base[NEXP] + i * 128; nt++; }
    *ntiles = nt;
    *base8out = base[NEXP];
  }
  __syncthreads();   // gtok/gsc clear complete before scatter

  if (act) {
#pragma unroll
    for (int i = 0; i < 16; i++) {
      int ent = t * 16 + i;
      int tok = ent >> 1;
      int k = ent & 1;
      int e = k ? e1[tok] : e0[tok];
      float s = k ? s1[tok] : s0[tok];
      int pos = base[e] + offl[t][e] + lrl[t][e];
      lrl[t][e]++;
      gtok[pos] = tok; gsc[pos] = s; row_of[ent] = pos;
    }
  }
  for (int i = t; i < NTOK; i += 512) { gtok[base[NEXP] + i] = i; gsc[base[NEXP] + i] = 1.0f; }
}

// ---------------- K3: gemm13 BK=64 + setprio (blocks 0..511) ∪ transpose(w2,w2s) ---------------
__global__ __launch_bounds__(512, 4) void gemm13_t2(
    const unsigned short* __restrict__ xbf,
    const unsigned short* __restrict__ W1, const unsigned short* __restrict__ W1s,
    const unsigned short* __restrict__ W3, const unsigned short* __restrict__ W3s,
    const float* __restrict__ w2, const float* __restrict__ w2s,
    unsigned short* __restrict__ w2t, unsigned short* __restrict__ w2st,
    unsigned short* __restrict__ H,
    const int* __restrict__ gtok, const float* __restrict__ gsc,
    const int* __restrict__ tile_e, const int* __restrict__ tile_r0,
    const int* __restrict__ ntiles) {
  __shared__ __align__(16) char smem[49664];   // union: 32KB transpose | 48.5KB gemm13
  int b = blockIdx.x;
  if (b >= 512) {
    int bb = b - 512;
    int slice = bb >> 6, s6 = bb & 63;
    int n_blk = s6 & 7, k_blk = s6 >> 3;
    const float* src; unsigned short* dst;
    if (slice < 8) { src = w2 + (size_t)slice * MM; dst = w2t + (size_t)slice * MM; }
    else           { src = w2s; dst = w2st; }
    brick_transpose(src, dst, n_blk, k_blk, (unsigned short*)smem);
    return;
  }
  int ti = b >> 3;
  if (ti >= *ntiles) return;
  int e = tile_e[ti];
  int row0 = tile_r0[ti];
  int col0 = (b & 7) * 128;
  const unsigned short* B1 = (e < NEXP) ? (W1 + (size_t)e * MM) : W1s;
  const unsigned short* B3 = (e < NEXP) ? (W3 + (size_t)e * MM) : W3s;

  unsigned short* As  = (unsigned short*)smem;            // 16KB (2 planes)
  unsigned short* Bs1 = (unsigned short*)(smem + 16384);  // 16KB
  unsigned short* Bs3 = (unsigned short*)(smem + 32768);  // 16KB
  float* ss = (float*)(smem + 49152);                     // 512B

  int tid = threadIdx.x;
  int wave = tid >> 6, lane = tid & 63;
  int wrow = (wave >> 2) * 64, wcol = (wave & 3) * 32;

  if (tid < 128) ss[tid] = gsc[row0 + tid];   // synced by first K-loop barrier

  f32x4 acc1[4][2], acc3[4][2];
#pragma unroll
  for (int m = 0; m < 4; m++)
#pragma unroll
    for (int n = 0; n < 2; n++) { acc1[m][n] = f32x4{0.f,0.f,0.f,0.f}; acc3[m][n] = f32x4{0.f,0.f,0.f,0.f}; }

  int arow = tid >> 2;
  int akoff = (((tid & 3) - (arow >> 1)) & 3) * 8;
  const unsigned short* ga  = xbf + (size_t)gtok[row0 + arow] * DIM + akoff;
  const unsigned short* gb1 = B1 + ((size_t)(col0 >> 7) * 32) * 4096 + (size_t)tid * 8;
  const unsigned short* gb3 = B3 + ((size_t)(col0 >> 7) * 32) * 4096 + (size_t)tid * 8;
  unsigned short* lA  = As  + wave * 512;
  unsigned short* lB1 = Bs1 + wave * 512;
  unsigned short* lB3 = Bs3 + wave * 512;

  int kc = lane >> 4, rl = lane & 15;

  for (int it = 0; it < 16; it++) {
    int k0 = it * 64;
    size_t boff = (size_t)(it * 2) * 4096;
    gload_lds16(ga + k0,      lA);
    gload_lds16(ga + k0 + 32, lA + 4096);
    gload_lds16(gb1 + boff,        lB1);
    gload_lds16(gb1 + boff + 4096, lB1 + 4096);
    gload_lds16(gb3 + boff,        lB3);
    gload_lds16(gb3 + boff + 4096, lB3 + 4096);
    __syncthreads();   // drains vmcnt before use

#pragma unroll
    for (int h = 0; h < 2; h++) {
      const bf16x8* Ap  = (const bf16x8*)As  + h * 512;
      const bf16x8* B1p = (const bf16x8*)Bs1 + h * 512;
      const bf16x8* B3p = (const bf16x8*)Bs3 + h * 512;
      bf16x8 af[4], b1f[2], b3f[2];
#pragma unroll
      for (int m = 0; m < 4; m++) {
        int row = wrow + m * 16 + rl;
        af[m] = Ap[row * 4 + ((kc + (row >> 1)) & 3)];
      }
#pragma unroll
      for (int n = 0; n < 2; n++) {
        int row = wcol + n * 16 + rl;
        int p = row * 4 + ((kc + (row >> 1)) & 3);
        b1f[n] = B1p[p];
        b3f[n] = B3p[p];
      }
      __builtin_amdgcn_s_setprio(1);   // T5: favor MFMA waves vs co-resident transpose waves
#pragma unroll
      for (int m = 0; m < 4; m++)
#pragma unroll
        for (int n = 0; n < 2; n++) {
          acc1[m][n] = __builtin_amdgcn_mfma_f32_16x16x32_bf16(af[m], b1f[n], acc1[m][n], 0, 0, 0);
          acc3[m][n] = __builtin_amdgcn_mfma_f32_16x16x32_bf16(af[m], b3f[n], acc3[m][n], 0, 0, 0);
        }
      __builtin_amdgcn_s_setprio(0);
    }
    __syncthreads();   // before next stage overwrites LDS
  }

  int rj = lane >> 4, cl = lane & 15;
#pragma unroll
  for (int m = 0; m < 4; m++)
#pragma unroll
    for (int n = 0; n < 2; n++)
#pragma unroll
      for (int j = 0; j < 4; j++) {
        int lr = wrow + m * 16 + rj * 4 + j;
        float s = ss[lr];
        float a = s * acc1[m][n][j];
        float g = s * acc3[m][n][j];
        float si = a / (1.f + __expf(-a));
        H[(size_t)(row0 + lr) * DIM + (col0 + wcol + n * 16 + cl)] = f2bf(si * g);
      }
}

// ---------------- gemm2 BK=64 (R15 form): routb = H * W2_e (bf16 out) --------------------------
__global__ __launch_bounds__(512, 4) void gemm2(
    const unsigned short* __restrict__ A, const unsigned short* __restrict__ W,
    const unsigned short* __restrict__ Wsh, unsigned short* __restrict__ C,
    const int* __restrict__ tile_e, const int* __restrict__ tile_r0,
    const int* __restrict__ ntiles) {
  if ((int)blockIdx.y >= *ntiles) return;
  int e = tile_e[blockIdx.y];
  int row0 = tile_r0[blockIdx.y];
  int col0 = blockIdx.x * 128;
  const unsigned short* B = (e < NEXP) ? (W + (size_t)e * MM) : Wsh;

  __shared__ __align__(16) unsigned short As[2 * 4096];   // 2 planes x [128][32]
  __shared__ __align__(16) unsigned short Bs[2 * 4096];

  int tid = threadIdx.x;
  int wave = tid >> 6, lane = tid & 63;
  int wrow = (wave & 3) * 32, wcol = (wave >> 2) * 64;

  f32x4 acc[2][4];
#pragma unroll
  for (int m = 0; m < 2; m++)
#pragma unroll
    for (int n = 0; n < 4; n++) acc[m][n] = f32x4{0.f, 0.f, 0.f, 0.f};

  int arow = tid >> 2;
  int akoff = (((tid & 3) - (arow >> 1)) & 3) * 8;
  const unsigned short* ga = A + (size_t)(row0 + arow) * DIM + akoff;
  const unsigned short* gb = B + ((size_t)(col0 >> 7) * 32) * 4096 + (size_t)tid * 8;
  unsigned short* lA = As + wave * 512;
  unsigned short* lB = Bs + wave * 512;

  int kc = lane >> 4, rl = lane & 15;

  for (int it = 0; it < 16; it++) {
    int k0 = it * 64;
    size_t boff = (size_t)(it * 2) * 4096;
    gload_lds16(ga + k0,      lA);
    gload_lds16(ga + k0 + 32, lA + 4096);
    gload_lds16(gb + boff,        lB);
    gload_lds16(gb + boff + 4096, lB + 4096);
    __syncthreads();

#pragma unroll
    for (int h = 0; h < 2; h++) {
      const bf16x8* Ap = (const bf16x8*)As + h * 512;
      const bf16x8* Bp = (const bf16x8*)Bs + h * 512;
      bf16x8 af[2], bfr[4];
#pragma unroll
      for (int m = 0; m < 2; m++) {
        int row = wrow + m * 16 + rl;
        af[m] = Ap[row * 4 + ((kc + (row >> 1)) & 3)];
      }
#pragma unroll
      for (int n = 0; n < 4; n++) {
        int row = wcol + n * 16 + rl;
        bfr[n] = Bp[row * 4 + ((kc + (row >> 1)) & 3)];
      }
#pragma unroll
      for (int m = 0; m < 2; m++)
#pragma unroll
        for (int n = 0; n < 4; n++)
          acc[m][n] = __builtin_amdgcn_mfma_f32_16x16x32_bf16(af[m], bfr[n], acc[m][n], 0, 0, 0);
    }
    __syncthreads();
  }

  int rj = lane >> 4, cl = lane & 15;
#pragma unroll
  for (int m = 0; m < 2; m++)
#pragma unroll
    for (int n = 0; n < 4; n++)
#pragma unroll
      for (int j = 0; j < 4; j++) {
        int r = row0 + wrow + m * 16 + rj * 4 + j;
        int c = col0 + wcol + n * 16 + cl;
        C[(size_t)r * DIM + c] = f2bf(acc[m][n][j]);
      }
}

// ---------------- combine: out[t] = routb[r0] + routb[r1] + routb[shared] (bf16 in) ------------
__global__ __launch_bounds__(256) void combine(const unsigned short* __restrict__ routb,
                                               const int* __restrict__ row_of,
                                               const int* __restrict__ base8,
                                               float* __restrict__ out) {
  int t = blockIdx.x;
  int c = threadIdx.x * 4;
  int r0 = row_of[2 * t], r1 = row_of[2 * t + 1];
  int rs = *base8 + t;
  ushort4 v0 = *(const ushort4*)(routb + (size_t)r0 * DIM + c);
  ushort4 v1 = *(const ushort4*)(routb + (size_t)r1 * DIM + c);
  ushort4 v2 = *(const ushort4*)(routb + (size_t)rs * DIM + c);
  float4 o;
  o.x = bf2f(v0.x) + bf2f(v1.x) + bf2f(v2.x);
  o.y = bf2f(v0.y) + bf2f(v1.y) + bf2f(v2.y);
  o.z = bf2f(v0.z) + bf2f(v1.z) + bf2f(v2.z);
  o.w = bf2f(v0.w) + bf2f(v1.w) + bf2f(v2.w);
  *(float4*)(out + (size_t)t * DIM + c) = o;
}

extern "C" void kernel_launch(void* const* d_in, const int* in_sizes, int n_in,
                              void* d_out, int out_size, void* d_ws, size_t ws_size,
                              hipStream_t stream) {
  const float* x   = (const float*)d_in[0];
  const float* gw  = (const float*)d_in[1];
  const float* w1  = (const float*)d_in[2];
  const float* w2  = (const float*)d_in[3];
  const float* w3  = (const float*)d_in[4];
  const float* w1s = (const float*)d_in[5];
  const float* w2s = (const float*)d_in[6];
  const float* w3s = (const float*)d_in[7];
  float* out = (float*)d_out;
  char* ws = (char*)d_ws;

  const size_t MB = 1ull << 20;
  unsigned short* w1t  = (unsigned short*)(ws + 0 * MB);    // 16MB [8] brick-layout W1^T
  unsigned short* w3t  = (unsigned short*)(ws + 16 * MB);   // 16MB
  unsigned short* w2t  = (unsigned short*)(ws + 32 * MB);   // 16MB
  unsigned short* w1st = (unsigned short*)(ws + 48 * MB);   // 2MB
  unsigned short* w3st = (unsigned short*)(ws + 50 * MB);   // 2MB
  unsigned short* w2st = (unsigned short*)(ws + 52 * MB);   // 2MB
  unsigned short* xbf  = (unsigned short*)(ws + 54 * MB);   // 4MB+  [NTOK+1][1024] bf16
  unsigned short* hbuf = (unsigned short*)(ws + 60 * MB);   // 16MB [8192][1024] bf16
  unsigned short* routb= (unsigned short*)(ws + 76 * MB);   // 16MB [8192][1024] bf16
  char* meta = ws + 108 * MB;
  int*   e0p    = (int*)meta;
  int*   e1p    = e0p + NTOK;
  float* s0p    = (float*)(e1p + NTOK);
  float* s1p    = s0p + NTOK;
  int*   gtok   = (int*)(s1p + NTOK);
  float* gsc    = (float*)(gtok + ROWS_CAP);
  int*   row_of = (int*)(gsc + ROWS_CAP);
  int*   tile_e = row_of + NENT;
  int*   tile_r0= tile_e + MAX_TILES;
  int*   ntiles = tile_r0 + MAX_TILES;
  int*   base8  = ntiles + 1;

  // K1: router (256 blocks) ∪ transpose w1[3..7]/w3/w1s/w3s (15 slices, 960 blocks)
  t13_router<<<256 + 15 * 64, 512, 0, stream>>>(
      x, gw, w1, w3, w1s, w3s, w1t, w3t, w1st, w3st, xbf, e0p, e1p, s0p, s1p);
  // K2: build (block 0) ∪ transpose w1[0..2] (192 blocks)
  build_t<<<1 + 3 * 64, 512, 0, stream>>>(e0p, e1p, s0p, s1p, w1, w1t,
                                          gtok, gsc, row_of, tile_e, tile_r0, ntiles, base8);
  // K3: gemm13 BK=64+setprio (512 blocks) ∪ transpose w2/w2s (576 blocks)
  gemm13_t2<<<512 + 9 * 64, 512, 0, stream>>>(
      xbf, w1t, w1st, w3t, w3st, w2, w2s, w2t, w2st, hbuf,
      gtok, gsc, tile_e, tile_r0, ntiles);
  // K4: gemm2 BK=64 (bf16 out)
  dim3 gg(8, MAX_TILES);
  gemm2<<<gg, 512, 0, stream>>>(hbuf, w2t, w2st, routb, tile_e, tile_r0, ntiles);
  // K5: combine
  combine<<<NTOK, 256, 0, stream>>>(routb, row_of, base8, out);
}

// Round 19
// 93.363 us; speedup vs baseline: 1.0626x; 1.0102x over previous
//
#include <hip/hip_runtime.h>
#include <hip/hip_bf16.h>

// MoE top-2 + shared expert, bf16 MFMA path. Round 19 (= R18 with compile fix:
// token-pasted float4 scalars replaced by statically-indexed float4 V[8] arrays).
// K1/K2 transpose = 4 tiles/block with register prefetch; inter-phase barriers
// are lgkmcnt(0)+raw s_barrier (no vmcnt drain -> prefetch loads fly across).
// K3 untouched (gemm occupancy preserved). Slice split: K1=15x16, K2=3x16, K3=9x64.

#define DIM 1024
#define NTOK 2048
#define NEXP 8
#define NENT 4096          // NTOK * 2
#define ROWS_CAP 8192      // padded grouped rows upper bound
#define MAX_TILES 64
#define MM (DIM * DIM)

typedef float f32x4 __attribute__((ext_vector_type(4)));
typedef __bf16 bf16x8 __attribute__((ext_vector_type(8)));

__device__ __forceinline__ unsigned short f2bf(float f) {
  unsigned int u = __builtin_bit_cast(unsigned int, f);
  unsigned int r = u + 0x7FFFu + ((u >> 16) & 1u);   // RNE
  return (unsigned short)(r >> 16);
}
__device__ __forceinline__ float bf2f(unsigned short h) {
  unsigned int u = ((unsigned int)h) << 16;
  return __builtin_bit_cast(float, u);
}
__device__ __forceinline__ void gload_lds16(const unsigned short* g, unsigned short* l) {
  __builtin_amdgcn_global_load_lds((__attribute__((address_space(1))) const void*)g,
                                   (__attribute__((address_space(3))) void*)l, 16, 0, 0);
}

// ---------------- brick transpose single-tile (R14 form; used by K3 union kernel) --------------
__device__ __forceinline__ void brick_transpose(const float* __restrict__ src,
                                                unsigned short* __restrict__ dst,
                                                int n_blk, int k_blk,
                                                unsigned short* lds) {
  int c0 = n_blk * 128, r0 = k_blk * 128;
  int tid = threadIdx.x;
  int q = tid & 31;
  int kq0 = tid >> 5;

  const float* sp0 = src + (size_t)(r0 + kq0 * 4) * DIM + c0 + q * 4;
  const float* sp1 = sp0 + (size_t)64 * DIM;
  float4 v0 = *(const float4*)(sp0 + 0 * DIM);
  float4 v1 = *(const float4*)(sp0 + 1 * DIM);
  float4 v2 = *(const float4*)(sp0 + 2 * DIM);
  float4 v3 = *(const float4*)(sp0 + 3 * DIM);
  float4 v4 = *(const float4*)(sp1 + 0 * DIM);
  float4 v5 = *(const float4*)(sp1 + 1 * DIM);
  float4 v6 = *(const float4*)(sp1 + 2 * DIM);
  float4 v7 = *(const float4*)(sp1 + 3 * DIM);
  {
    float a0[4] = {v0.x, v0.y, v0.z, v0.w};
    float a1[4] = {v1.x, v1.y, v1.z, v1.w};
    float a2[4] = {v2.x, v2.y, v2.z, v2.w};
    float a3[4] = {v3.x, v3.y, v3.z, v3.w};
    float b0[4] = {v4.x, v4.y, v4.z, v4.w};
    float b1[4] = {v5.x, v5.y, v5.z, v5.w};
    float b2[4] = {v6.x, v6.y, v6.z, v6.w};
    float b3[4] = {v7.x, v7.y, v7.z, v7.w};
#pragma unroll
    for (int j = 0; j < 4; j++) {
      int row = q * 4 + j;
      {
        int kq = kq0;
        int ch = kq >> 1, half = kq & 1;
        unsigned int off = (unsigned int)row * 128 + ((ch ^ (row & 15)) * 8 + half * 4);
        uint2 p;
        p.x = f2bf(a0[j]) | ((unsigned int)f2bf(a1[j]) << 16);
        p.y = f2bf(a2[j]) | ((unsigned int)f2bf(a3[j]) << 16);
        *(uint2*)(lds + off) = p;
      }
      {
        int kq = kq0 + 16;
        int ch = kq >> 1, half = kq & 1;
        unsigned int off = (unsigned int)row * 128 + ((ch ^ (row & 15)) * 8 + half * 4);
        uint2 p;
        p.x = f2bf(b0[j]) | ((unsigned int)f2bf(b1[j]) << 16);
        p.y = f2bf(b2[j]) | ((unsigned int)f2bf(b3[j]) << 16);
        *(uint2*)(lds + off) = p;
      }
    }
  }
  __syncthreads();

  size_t bbase = ((size_t)n_blk * 32 + (size_t)k_blk * 4) * 4096;
#pragma unroll
  for (int i = 0; i < 4; i++) {
    int g = tid + i * 512;
    int kcr = g >> 9;
    int c = g & 511;
    int row = c >> 2, p = c & 3;
    int koff = (p - (row >> 1)) & 3;
    int ch = kcr * 4 + koff;
    uint4 val = *(const uint4*)(lds + (unsigned int)row * 128 + (ch ^ (row & 15)) * 8);
    *(uint4*)(dst + bbase + (size_t)g * 8) = val;
  }
}

// ---------------- brick transpose 4-tile pipelined (K1/K2): same k-band, 4 n-columns -----------
// Register-prefetch next tile's loads; barriers wait lgkm only (vmem flies across).
#define BT4_LOAD(V, NB)                                                       \
  { const float* sp0_ = src + (size_t)(r0 + kq0 * 4) * DIM + (NB) * 128 + q * 4; \
    const float* sp1_ = sp0_ + (size_t)64 * DIM;                              \
    V[0] = *(const float4*)(sp0_ + 0 * DIM);                                  \
    V[1] = *(const float4*)(sp0_ + 1 * DIM);                                  \
    V[2] = *(const float4*)(sp0_ + 2 * DIM);                                  \
    V[3] = *(const float4*)(sp0_ + 3 * DIM);                                  \
    V[4] = *(const float4*)(sp1_ + 0 * DIM);                                  \
    V[5] = *(const float4*)(sp1_ + 1 * DIM);                                  \
    V[6] = *(const float4*)(sp1_ + 2 * DIM);                                  \
    V[7] = *(const float4*)(sp1_ + 3 * DIM); }

#define BT4_PACK(V)                                                           \
  { float a0_[4] = {V[0].x, V[0].y, V[0].z, V[0].w};                          \
    float a1_[4] = {V[1].x, V[1].y, V[1].z, V[1].w};                          \
    float a2_[4] = {V[2].x, V[2].y, V[2].z, V[2].w};                          \
    float a3_[4] = {V[3].x, V[3].y, V[3].z, V[3].w};                          \
    float b0_[4] = {V[4].x, V[4].y, V[4].z, V[4].w};                          \
    float b1_[4] = {V[5].x, V[5].y, V[5].z, V[5].w};                          \
    float b2_[4] = {V[6].x, V[6].y, V[6].z, V[6].w};                          \
    float b3_[4] = {V[7].x, V[7].y, V[7].z, V[7].w};                          \
    _Pragma("unroll")                                                         \
    for (int j = 0; j < 4; j++) {                                             \
      int row = q * 4 + j;                                                    \
      { int ch = kq0 >> 1, half = kq0 & 1;                                    \
        unsigned int off = (unsigned int)row * 128 + ((ch ^ (row & 15)) * 8 + half * 4); \
        uint2 p_;                                                             \
        p_.x = f2bf(a0_[j]) | ((unsigned int)f2bf(a1_[j]) << 16);             \
        p_.y = f2bf(a2_[j]) | ((unsigned int)f2bf(a3_[j]) << 16);             \
        *(uint2*)(lds + off) = p_; }                                          \
      { int kq = kq0 + 16; int ch = kq >> 1, half = kq & 1;                   \
        unsigned int off = (unsigned int)row * 128 + ((ch ^ (row & 15)) * 8 + half * 4); \
        uint2 p_;                                                             \
        p_.x = f2bf(b0_[j]) | ((unsigned int)f2bf(b1_[j]) << 16);             \
        p_.y = f2bf(b2_[j]) | ((unsigned int)f2bf(b3_[j]) << 16);             \
        *(uint2*)(lds + off) = p_; } } }

#define BT4_FENCE                                            \
  { asm volatile("s_waitcnt lgkmcnt(0)" ::: "memory");       \
    __builtin_amdgcn_s_barrier(); }

#define BT4_PHASE2(NB)                                                        \
  { size_t bbase_ = ((size_t)(NB) * 32 + (size_t)k_blk * 4) * 4096;           \
    _Pragma("unroll")                                                         \
    for (int i = 0; i < 4; i++) {                                             \
      int g = tid + i * 512;                                                  \
      int kcr = g >> 9;                                                       \
      int c = g & 511;                                                        \
      int row = c >> 2, p = c & 3;                                            \
      int koff = (p - (row >> 1)) & 3;                                        \
      int ch = kcr * 4 + koff;                                                \
      uint4 val = *(const uint4*)(lds + (unsigned int)row * 128 + (ch ^ (row & 15)) * 8); \
      *(uint4*)(dst + bbase_ + (size_t)g * 8) = val;                          \
    } }

__device__ __forceinline__ void brick_transpose4(const float* __restrict__ src,
                                                 unsigned short* __restrict__ dst,
                                                 int k_blk, int nb0,
                                                 unsigned short* lds) {
  int tid = threadIdx.x;
  int q = tid & 31;
  int kq0 = tid >> 5;
  int r0 = k_blk * 128;
  float4 va[8], vb[8];

  BT4_LOAD(va, nb0 + 0);
  BT4_LOAD(vb, nb0 + 1);                 // prefetch tile 1
  BT4_PACK(va);  BT4_FENCE;  BT4_PHASE2(nb0 + 0);  BT4_FENCE;
  BT4_LOAD(va, nb0 + 2);                 // prefetch tile 2
  BT4_PACK(vb);  BT4_FENCE;  BT4_PHASE2(nb0 + 1);  BT4_FENCE;
  BT4_LOAD(vb, nb0 + 3);                 // prefetch tile 3
  BT4_PACK(va);  BT4_FENCE;  BT4_PHASE2(nb0 + 2);  BT4_FENCE;
  BT4_PACK(vb);  BT4_FENCE;  BT4_PHASE2(nb0 + 3);
}

// ---------------- K1: router (blocks 0..255) ∪ transpose4 (15 slices x 16 blocks) --------------
__global__ __launch_bounds__(512, 2) void t13_router(
    const float* __restrict__ x, const float* __restrict__ gw,
    const float* __restrict__ w1, const float* __restrict__ w3,
    const float* __restrict__ w1s, const float* __restrict__ w3s,
    unsigned short* __restrict__ w1t, unsigned short* __restrict__ w3t,
    unsigned short* __restrict__ w1st, unsigned short* __restrict__ w3st,
    unsigned short* __restrict__ xbf,
    int* __restrict__ e0, int* __restrict__ e1,
    float* __restrict__ s0, float* __restrict__ s1) {
  __shared__ __align__(16) unsigned short lds[128 * 128];
  int b = blockIdx.x;
  if (b < 256) {
    int lane = threadIdx.x & 63;
    int t = b * 8 + (threadIdx.x >> 6);
    const float4* xr4 = (const float4*)(x + (size_t)t * DIM);
    float4 xv[4];
#pragma unroll
    for (int i = 0; i < 4; i++) xv[i] = xr4[i * 64 + lane];

    ushort4* xb4 = (ushort4*)(xbf + (size_t)t * DIM);
#pragma unroll
    for (int i = 0; i < 4; i++) {
      ushort4 o;
      o.x = f2bf(xv[i].x); o.y = f2bf(xv[i].y); o.z = f2bf(xv[i].z); o.w = f2bf(xv[i].w);
      xb4[i * 64 + lane] = o;
    }
    if (t == 0) {
      ushort4 zz; zz.x = zz.y = zz.z = zz.w = 0;
      ushort4* pb4 = (ushort4*)(xbf + (size_t)NTOK * DIM);
#pragma unroll
      for (int i = 0; i < 4; i++) pb4[i * 64 + lane] = zz;
    }

    float acc[NEXP];
#pragma unroll
    for (int e = 0; e < NEXP; e++) {
      const float4* g4 = (const float4*)(gw + (size_t)e * DIM);
      float a = 0.f;
#pragma unroll
      for (int i = 0; i < 4; i++) {
        float4 g = g4[i * 64 + lane];
        a += xv[i].x * g.x + xv[i].y * g.y + xv[i].z * g.z + xv[i].w * g.w;
      }
      acc[e] = a;
    }
#pragma unroll
    for (int e = 0; e < NEXP; e++) {
      float v = acc[e];
      for (int o = 32; o > 0; o >>= 1) v += __shfl_xor(v, o);
      acc[e] = v;
    }
    if (lane == 0) {
      float m = acc[0];
#pragma unroll
      for (int e = 1; e < NEXP; e++) m = fmaxf(m, acc[e]);
      float ex[NEXP]; float Z = 0.f;
#pragma unroll
      for (int e = 0; e < NEXP; e++) { ex[e] = __expf(acc[e] - m); Z += ex[e]; }
      float inv = 1.f / Z;
      float sc[NEXP];
#pragma unroll
      for (int e = 0; e < NEXP; e++) sc[e] = ex[e] * inv;
      int b0 = 0; float v0 = sc[0];
#pragma unroll
      for (int e = 1; e < NEXP; e++) if (sc[e] > v0) { v0 = sc[e]; b0 = e; }
      int b1 = -1; float v1 = -1.f;
#pragma unroll
      for (int e = 0; e < NEXP; e++) if (e != b0 && sc[e] > v1) { v1 = sc[e]; b1 = e; }
      e0[t] = b0; e1[t] = b1; s0[t] = v0; s1[t] = v1;
    }
  } else {
    int bb = b - 256;
    int slice = bb >> 4, s16 = bb & 15;
    int k_blk = s16 >> 1, nb0 = (s16 & 1) * 4;
    const float* src; unsigned short* dst;
    if (slice < 5)       { src = w1 + (size_t)(slice + 3) * MM; dst = w1t + (size_t)(slice + 3) * MM; }
    else if (slice < 13) { src = w3 + (size_t)(slice - 5) * MM; dst = w3t + (size_t)(slice - 5) * MM; }
    else if (slice == 13){ src = w1s; dst = w1st; }
    else                 { src = w3s; dst = w3st; }
    brick_transpose4(src, dst, k_blk, nb0, lds);
  }
}

// ---------------- K2: build_groups (block 0) ∪ transpose4(w1[0..2]: 48 blocks) -----------------
__global__ __launch_bounds__(512, 2) void build_t(
    const int* __restrict__ e0, const int* __restrict__ e1,
    const float* __restrict__ s0, const float* __restrict__ s1,
    const float* __restrict__ w1, unsigned short* __restrict__ w1t,
    int* __restrict__ gtok, float* __restrict__ gsc, int* __restrict__ row_of,
    int* __restrict__ tile_e, int* __restrict__ tile_r0, int* __restrict__ ntiles,
    int* __restrict__ base8out) {
  __shared__ __align__(16) unsigned short lds[128 * 128];   // transpose role (32KB)
  __shared__ unsigned int wsum[4][4];
  __shared__ int offl[256][NEXP];
  __shared__ int lrl[256][NEXP];

  int b = blockIdx.x;
  if (b > 0) {
    int bb = b - 1;
    int slice = bb >> 4, s16 = bb & 15;
    brick_transpose4(w1 + (size_t)slice * MM, w1t + (size_t)slice * MM,
                     s16 >> 1, (s16 & 1) * 4, lds);
    return;
  }

  int t = threadIdx.x, lane = t & 63, wave = t >> 6;
  bool act = t < 256;

  for (int i = t; i < ROWS_CAP; i += 512) { gtok[i] = NTOK; gsc[i] = 0.f; }  // pad -> zero row

  unsigned int pc[4] = {0, 0, 0, 0};
  if (act) {
#pragma unroll
    for (int i = 0; i < 16; i++) {
      int ent = t * 16 + i;
      int tok = ent >> 1;
      int e = (ent & 1) ? e1[tok] : e0[tok];
      unsigned int add = 1u << ((e & 1) * 16);
      int c = e >> 1;
      if (c == 0) pc[0] += add; else if (c == 1) pc[1] += add;
      else if (c == 2) pc[2] += add; else pc[3] += add;
    }
  }
  unsigned int incl[4] = {pc[0], pc[1], pc[2], pc[3]};
#pragma unroll
  for (int o = 1; o < 64; o <<= 1) {
    unsigned int u0 = __shfl_up(incl[0], o), u1 = __shfl_up(incl[1], o);
    unsigned int u2 = __shfl_up(incl[2], o), u3 = __shfl_up(incl[3], o);
    if (lane >= o) { incl[0] += u0; incl[1] += u1; incl[2] += u2; incl[3] += u3; }
  }
  if (act && lane == 63) { wsum[wave][0] = incl[0]; wsum[wave][1] = incl[1];
                           wsum[wave][2] = incl[2]; wsum[wave][3] = incl[3]; }
  __syncthreads();
  unsigned int T[4], pre[4] = {0, 0, 0, 0};
#pragma unroll
  for (int c = 0; c < 4; c++)
    T[c] = wsum[0][c] + wsum[1][c] + wsum[2][c] + wsum[3][c];
#pragma unroll
  for (int w = 0; w < 3; w++)
    if (wave > w) { pre[0] += wsum[w][0]; pre[1] += wsum[w][1];
                    pre[2] += wsum[w][2]; pre[3] += wsum[w][3]; }
  int base[NEXP + 1];
  {
    int bsum = 0;
#pragma unroll
    for (int e = 0; e < NEXP; e++) {
      int tot = (int)((T[e >> 1] >> ((e & 1) * 16)) & 0xFFFFu);
      base[e] = bsum; bsum += (tot + 127) & ~127;
    }
    base[NEXP] = bsum;
  }
  if (act) {
#pragma unroll
    for (int e = 0; e < NEXP; e++) {
      unsigned int ex = (incl[e >> 1] + pre[e >> 1] - pc[e >> 1]);
      offl[t][e] = (int)((ex >> ((e & 1) * 16)) & 0xFFFFu);
      lrl[t][e] = 0;
    }
  }
  if (t == 0) {
    int nt = 0;
#pragma unroll
    for (int e = 0; e < NEXP; e++) {
      int tot = (int)((T[e >> 1] >> ((e & 1) * 16)) & 0xFFFFu);
      int ntl = (tot + 127) >> 7;
      for (int i = 0; i < ntl; i++) { tile_e[nt] = e; tile_r0[nt] = base[e] + i * 128; nt++; }
    }
    for (int i = 0; i < NTOK / 128; i++) { tile_e[nt] = NEXP; tile_r0[nt] = base[NEXP] + i * 128; nt++; }
    *ntiles = nt;
    *base8out = base[NEXP];
  }
  __syncthreads();   // gtok/gsc clear complete before scatter

  if (act) {
#pragma unroll
    for (int i = 0; i < 16; i++) {
      int ent = t * 16 + i;
      int tok = ent >> 1;
      int k = ent & 1;
      int e = k ? e1[tok] : e0[tok];
      float s = k ? s1[tok] : s0[tok];
      int pos = base[e] + offl[t][e] + lrl[t][e];
      lrl[t][e]++;
      gtok[pos] = tok; gsc[pos] = s; row_of[ent] = pos;
    }
  }
  for (int i = t; i < NTOK; i += 512) { gtok[base[NEXP] + i] = i; gsc[base[NEXP] + i] = 1.0f; }
}

// ---------------- K3: gemm13 BK=64 + setprio (blocks 0..511) ∪ transpose(w2,w2s) ---------------
__global__ __launch_bounds__(512, 4) void gemm13_t2(
    const unsigned short* __restrict__ xbf,
    const unsigned short* __restrict__ W1, const unsigned short* __restrict__ W1s,
    const unsigned short* __restrict__ W3, const unsigned short* __restrict__ W3s,
    const float* __restrict__ w2, const float* __restrict__ w2s,
    unsigned short* __restrict__ w2t, unsigned short* __restrict__ w2st,
    unsigned short* __restrict__ H,
    const int* __restrict__ gtok, const float* __restrict__ gsc,
    const int* __restrict__ tile_e, const int* __restrict__ tile_r0,
    const int* __restrict__ ntiles) {
  __shared__ __align__(16) char smem[49664];   // union: 32KB transpose | 48.5KB gemm13
  int b = blockIdx.x;
  if (b >= 512) {
    int bb = b - 512;
    int slice = bb >> 6, s6 = bb & 63;
    int n_blk = s6 & 7, k_blk = s6 >> 3;
    const float* src; unsigned short* dst;
    if (slice < 8) { src = w2 + (size_t)slice * MM; dst = w2t + (size_t)slice * MM; }
    else           { src = w2s; dst = w2st; }
    brick_transpose(src, dst, n_blk, k_blk, (unsigned short*)smem);
    return;
  }
  int ti = b >> 3;
  if (ti >= *ntiles) return;
  int e = tile_e[ti];
  int row0 = tile_r0[ti];
  int col0 = (b & 7) * 128;
  const unsigned short* B1 = (e < NEXP) ? (W1 + (size_t)e * MM) : W1s;
  const unsigned short* B3 = (e < NEXP) ? (W3 + (size_t)e * MM) : W3s;

  unsigned short* As  = (unsigned short*)smem;            // 16KB (2 planes)
  unsigned short* Bs1 = (unsigned short*)(smem + 16384);  // 16KB
  unsigned short* Bs3 = (unsigned short*)(smem + 32768);  // 16KB
  float* ss = (float*)(smem + 49152);                     // 512B

  int tid = threadIdx.x;
  int wave = tid >> 6, lane = tid & 63;
  int wrow = (wave >> 2) * 64, wcol = (wave & 3) * 32;

  if (tid < 128) ss[tid] = gsc[row0 + tid];   // synced by first K-loop barrier

  f32x4 acc1[4][2], acc3[4][2];
#pragma unroll
  for (int m = 0; m < 4; m++)
#pragma unroll
    for (int n = 0; n < 2; n++) { acc1[m][n] = f32x4{0.f,0.f,0.f,0.f}; acc3[m][n] = f32x4{0.f,0.f,0.f,0.f}; }

  int arow = tid >> 2;
  int akoff = (((tid & 3) - (arow >> 1)) & 3) * 8;
  const unsigned short* ga  = xbf + (size_t)gtok[row0 + arow] * DIM + akoff;
  const unsigned short* gb1 = B1 + ((size_t)(col0 >> 7) * 32) * 4096 + (size_t)tid * 8;
  const unsigned short* gb3 = B3 + ((size_t)(col0 >> 7) * 32) * 4096 + (size_t)tid * 8;
  unsigned short* lA  = As  + wave * 512;
  unsigned short* lB1 = Bs1 + wave * 512;
  unsigned short* lB3 = Bs3 + wave * 512;

  int kc = lane >> 4, rl = lane & 15;

  for (int it = 0; it < 16; it++) {
    int k0 = it * 64;
    size_t boff = (size_t)(it * 2) * 4096;
    gload_lds16(ga + k0,      lA);
    gload_lds16(ga + k0 + 32, lA + 4096);
    gload_lds16(gb1 + boff,        lB1);
    gload_lds16(gb1 + boff + 4096, lB1 + 4096);
    gload_lds16(gb3 + boff,        lB3);
    gload_lds16(gb3 + boff + 4096, lB3 + 4096);
    __syncthreads();   // drains vmcnt before use

#pragma unroll
    for (int h = 0; h < 2; h++) {
      const bf16x8* Ap  = (const bf16x8*)As  + h * 512;
      const bf16x8* B1p = (const bf16x8*)Bs1 + h * 512;
      const bf16x8* B3p = (const bf16x8*)Bs3 + h * 512;
      bf16x8 af[4], b1f[2], b3f[2];
#pragma unroll
      for (int m = 0; m < 4; m++) {
        int row = wrow + m * 16 + rl;
        af[m] = Ap[row * 4 + ((kc + (row >> 1)) & 3)];
      }
#pragma unroll
      for (int n = 0; n < 2; n++) {
        int row = wcol + n * 16 + rl;
        int p = row * 4 + ((kc + (row >> 1)) & 3);
        b1f[n] = B1p[p];
        b3f[n] = B3p[p];
      }
      __builtin_amdgcn_s_setprio(1);   // T5: favor MFMA waves vs co-resident transpose waves
#pragma unroll
      for (int m = 0; m < 4; m++)
#pragma unroll
        for (int n = 0; n < 2; n++) {
          acc1[m][n] = __builtin_amdgcn_mfma_f32_16x16x32_bf16(af[m], b1f[n], acc1[m][n], 0, 0, 0);
          acc3[m][n] = __builtin_amdgcn_mfma_f32_16x16x32_bf16(af[m], b3f[n], acc3[m][n], 0, 0, 0);
        }
      __builtin_amdgcn_s_setprio(0);
    }
    __syncthreads();   // before next stage overwrites LDS
  }

  int rj = lane >> 4, cl = lane & 15;
#pragma unroll
  for (int m = 0; m < 4; m++)
#pragma unroll
    for (int n = 0; n < 2; n++)
#pragma unroll
      for (int j = 0; j < 4; j++) {
        int lr = wrow + m * 16 + rj * 4 + j;
        float s = ss[lr];
        float a = s * acc1[m][n][j];
        float g = s * acc3[m][n][j];
        float si = a / (1.f + __expf(-a));
        H[(size_t)(row0 + lr) * DIM + (col0 + wcol + n * 16 + cl)] = f2bf(si * g);
      }
}

// ---------------- gemm2 BK=64 (R15 form): routb = H * W2_e (bf16 out) --------------------------
__global__ __launch_bounds__(512, 4) void gemm2(
    const unsigned short* __restrict__ A, const unsigned short* __restrict__ W,
    const unsigned short* __restrict__ Wsh, unsigned short* __restrict__ C,
    const int* __restrict__ tile_e, const int* __restrict__ tile_r0,
    const int* __restrict__ ntiles) {
  if ((int)blockIdx.y >= *ntiles) return;
  int e = tile_e[blockIdx.y];
  int row0 = tile_r0[blockIdx.y];
  int col0 = blockIdx.x * 128;
  const unsigned short* B = (e < NEXP) ? (W + (size_t)e * MM) : Wsh;

  __shared__ __align__(16) unsigned short As[2 * 4096];   // 2 planes x [128][32]
  __shared__ __align__(16) unsigned short Bs[2 * 4096];

  int tid = threadIdx.x;
  int wave = tid >> 6, lane = tid & 63;
  int wrow = (wave & 3) * 32, wcol = (wave >> 2) * 64;

  f32x4 acc[2][4];
#pragma unroll
  for (int m = 0; m < 2; m++)
#pragma unroll
    for (int n = 0; n < 4; n++) acc[m][n] = f32x4{0.f, 0.f, 0.f, 0.f};

  int arow = tid >> 2;
  int akoff = (((tid & 3) - (arow >> 1)) & 3) * 8;
  const unsigned short* ga = A + (size_t)(row0 + arow) * DIM + akoff;
  const unsigned short* gb = B + ((size_t)(col0 >> 7) * 32) * 4096 + (size_t)tid * 8;
  unsigned short* lA = As + wave * 512;
  unsigned short* lB = Bs + wave * 512;

  int kc = lane >> 4, rl = lane & 15;

  for (int it = 0; it < 16; it++) {
    int k0 = it * 64;
    size_t boff = (size_t)(it * 2) * 4096;
    gload_lds16(ga + k0,      lA);
    gload_lds16(ga + k0 + 32, lA + 4096);
    gload_lds16(gb + boff,        lB);
    gload_lds16(gb + boff + 4096, lB + 4096);
    __syncthreads();

#pragma unroll
    for (int h = 0; h < 2; h++) {
      const bf16x8* Ap = (const bf16x8*)As + h * 512;
      const bf16x8* Bp = (const bf16x8*)Bs + h * 512;
      bf16x8 af[2], bfr[4];
#pragma unroll
      for (int m = 0; m < 2; m++) {
        int row = wrow + m * 16 + rl;
        af[m] = Ap[row * 4 + ((kc + (row >> 1)) & 3)];
      }
#pragma unroll
      for (int n = 0; n < 4; n++) {
        int row = wcol + n * 16 + rl;
        bfr[n] = Bp[row * 4 + ((kc + (row >> 1)) & 3)];
      }
#pragma unroll
      for (int m = 0; m < 2; m++)
#pragma unroll
        for (int n = 0; n < 4; n++)
          acc[m][n] = __builtin_amdgcn_mfma_f32_16x16x32_bf16(af[m], bfr[n], acc[m][n], 0, 0, 0);
    }
    __syncthreads();
  }

  int rj = lane >> 4, cl = lane & 15;
#pragma unroll
  for (int m = 0; m < 2; m++)
#pragma unroll
    for (int n = 0; n < 4; n++)
#pragma unroll
      for (int j = 0; j < 4; j++) {
        int r = row0 + wrow + m * 16 + rj * 4 + j;
        int c = col0 + wcol + n * 16 + cl;
        C[(size_t)r * DIM + c] = f2bf(acc[m][n][j]);
      }
}

// ---------------- combine: out[t] = routb[r0] + routb[r1] + routb[shared] (bf16 in) ------------
__global__ __launch_bounds__(256) void combine(const unsigned short* __restrict__ routb,
                                               const int* __restrict__ row_of,
                                               const int* __restrict__ base8,
                                               float* __restrict__ out) {
  int t = blockIdx.x;
  int c = threadIdx.x * 4;
  int r0 = row_of[2 * t], r1 = row_of[2 * t + 1];
  int rs = *base8 + t;
  ushort4 v0 = *(const ushort4*)(routb + (size_t)r0 * DIM + c);
  ushort4 v1 = *(const ushort4*)(routb + (size_t)r1 * DIM + c);
  ushort4 v2 = *(const ushort4*)(routb + (size_t)rs * DIM + c);
  float4 o;
  o.x = bf2f(v0.x) + bf2f(v1.x) + bf2f(v2.x);
  o.y = bf2f(v0.y) + bf2f(v1.y) + bf2f(v2.y);
  o.z = bf2f(v0.z) + bf2f(v1.z) + bf2f(v2.z);
  o.w = bf2f(v0.w) + bf2f(v1.w) + bf2f(v2.w);
  *(float4*)(out + (size_t)t * DIM + c) = o;
}

extern "C" void kernel_launch(void* const* d_in, const int* in_sizes, int n_in,
                              void* d_out, int out_size, void* d_ws, size_t ws_size,
                              hipStream_t stream) {
  const float* x   = (const float*)d_in[0];
  const float* gw  = (const float*)d_in[1];
  const float* w1  = (const float*)d_in[2];
  const float* w2  = (const float*)d_in[3];
  const float* w3  = (const float*)d_in[4];
  const float* w1s = (const float*)d_in[5];
  const float* w2s = (const float*)d_in[6];
  const float* w3s = (const float*)d_in[7];
  float* out = (float*)d_out;
  char* ws = (char*)d_ws;

  const size_t MB = 1ull << 20;
  unsigned short* w1t  = (unsigned short*)(ws + 0 * MB);    // 16MB [8] brick-layout W1^T
  unsigned short* w3t  = (unsigned short*)(ws + 16 * MB);   // 16MB
  unsigned short* w2t  = (unsigned short*)(ws + 32 * MB);   // 16MB
  unsigned short* w1st = (unsigned short*)(ws + 48 * MB);   // 2MB
  unsigned short* w3st = (unsigned short*)(ws + 50 * MB);   // 2MB
  unsigned short* w2st = (unsigned short*)(ws + 52 * MB);   // 2MB
  unsigned short* xbf  = (unsigned short*)(ws + 54 * MB);   // 4MB+  [NTOK+1][1024] bf16
  unsigned short* hbuf = (unsigned short*)(ws + 60 * MB);   // 16MB [8192][1024] bf16
  unsigned short* routb= (unsigned short*)(ws + 76 * MB);   // 16MB [8192][1024] bf16
  char* meta = ws + 108 * MB;
  int*   e0p    = (int*)meta;
  int*   e1p    = e0p + NTOK;
  float* s0p    = (float*)(e1p + NTOK);
  float* s1p    = s0p + NTOK;
  int*   gtok   = (int*)(s1p + NTOK);
  float* gsc    = (float*)(gtok + ROWS_CAP);
  int*   row_of = (int*)(gsc + ROWS_CAP);
  int*   tile_e = row_of + NENT;
  int*   tile_r0= tile_e + MAX_TILES;
  int*   ntiles = tile_r0 + MAX_TILES;
  int*   base8  = ntiles + 1;

  // K1: router (256 blocks) ∪ transpose4 w1[3..7]/w3/w1s/w3s (15 slices x 16 = 240 blocks)
  t13_router<<<256 + 15 * 16, 512, 0, stream>>>(
      x, gw, w1, w3, w1s, w3s, w1t, w3t, w1st, w3st, xbf, e0p, e1p, s0p, s1p);
  // K2: build (block 0) ∪ transpose4 w1[0..2] (48 blocks)
  build_t<<<1 + 3 * 16, 512, 0, stream>>>(e0p, e1p, s0p, s1p, w1, w1t,
                                          gtok, gsc, row_of, tile_e, tile_r0, ntiles, base8);
  // K3: gemm13 BK=64+setprio (512 blocks) ∪ transpose w2/w2s (576 blocks, old form)
  gemm13_t2<<<512 + 9 * 64, 512, 0, stream>>>(
      xbf, w1t, w1st, w3t, w3st, w2, w2s, w2t, w2st, hbuf,
      gtok, gsc, tile_e, tile_r0, ntiles);
  // K4: gemm2 BK=64 (bf16 out)
  dim3 gg(8, MAX_TILES);
  gemm2<<<gg, 512, 0, stream>>>(hbuf, w2t, w2st, routb, tile_e, tile_r0, ntiles);
  // K5: combine
  combine<<<NTOK, 256, 0, stream>>>(routb, row_of, base8, out);
}